// Round 1
// baseline (173.130 us; speedup 1.0000x reference)
//
#include <hip/hip_runtime.h>
#include <math.h>

#define NB 4096
#define ND 1024
#define SCALEF 20.0f
#define TILES 32   // 4096 / 128 tiles per dimension

typedef __bf16 bf16_t;
typedef bf16_t bf16x8 __attribute__((ext_vector_type(8)));
typedef float floatx4 __attribute__((ext_vector_type(4)));

// ---------------------------------------------------------------------------
// Kernel 1: per-row inverse L2 norms (clamped at eps) for both matrices.
// One block of 256 threads per row; inv_norms[0..4095] = anchor,
// inv_norms[4096..8191] = pos_negs.
// ---------------------------------------------------------------------------
__global__ __launch_bounds__(256) void mnrl_norms(const float* __restrict__ A,
                                                  const float* __restrict__ P,
                                                  float* __restrict__ inv_norms) {
    int row = blockIdx.x;  // 0..8191
    const float* src = (row < NB) ? (A + (size_t)row * ND)
                                  : (P + (size_t)(row - NB) * ND);
    int t = threadIdx.x;
    float4 v = ((const float4*)src)[t];  // 256 threads * 4 floats = 1024
    float ss = v.x * v.x + v.y * v.y + v.z * v.z + v.w * v.w;
#pragma unroll
    for (int off = 32; off > 0; off >>= 1) ss += __shfl_down(ss, off, 64);
    __shared__ float sred[4];
    if ((t & 63) == 0) sred[t >> 6] = ss;
    __syncthreads();
    if (t == 0) {
        float tot = sred[0] + sred[1] + sred[2] + sred[3];
        inv_norms[row] = 1.0f / fmaxf(sqrtf(tot), 1e-8f);
    }
}

// ---------------------------------------------------------------------------
// Kernel 2: 128x128-tile bf16 MFMA GEMM with fused exp-sum (fixed shift 20)
// and diagonal extraction. Normalization scales folded into the epilogue.
// Block = 256 threads = 4 waves in 2x2; each wave does a 64x64 subtile as
// 4x4 grid of mfma_f32_16x16x32_bf16. LDS tiles: [128 rows][32 k] bf16.
// ---------------------------------------------------------------------------
__global__ __launch_bounds__(256) void mnrl_gemm_lse(
    const float* __restrict__ A, const float* __restrict__ P,
    const float* __restrict__ inv_a, const float* __restrict__ inv_p,
    float* __restrict__ rowsum, float* __restrict__ diag) {
    __shared__ __align__(16) bf16_t lds_a[128 * 32];
    __shared__ __align__(16) bf16_t lds_b[128 * 32];

    // GROUP_M=8 swizzle for L2 locality
    int pid = blockIdx.x;
    const int num_in_group = 8 * TILES;
    int group_id = pid / num_in_group;
    int first_m = group_id * 8;
    int tile_m = first_m + (pid % 8);
    int tile_n = (pid % num_in_group) / 8;

    int t = threadIdx.x;
    int lane = t & 63;
    int wave = t >> 6;
    int wm = wave >> 1, wn = wave & 1;
    int quad = lane >> 4;
    int l16 = lane & 15;

    const float* Abase = A + (size_t)tile_m * 128 * ND;
    const float* Pbase = P + (size_t)tile_n * 128 * ND;

    floatx4 acc[4][4];
#pragma unroll
    for (int i = 0; i < 4; ++i)
#pragma unroll
        for (int j = 0; j < 4; ++j) acc[i][j] = (floatx4){0.f, 0.f, 0.f, 0.f};

    for (int k0 = 0; k0 < ND; k0 += 32) {
        __syncthreads();
        // Stage A and B tiles: 128 rows x 32 cols of fp32 -> bf16 LDS.
        // Thread e handles row e>>2, 8-float chunk (e&3). Coalesced global
        // reads; LDS b128 writes land uniformly on all 32 banks.
#pragma unroll
        for (int i = 0; i < 2; ++i) {
            int e = t + i * 256;       // 0..511
            int r = e >> 2;            // 0..127
            int c8 = (e & 3) * 8;      // 0,8,16,24
            const float* ga = Abase + (size_t)r * ND + k0 + c8;
            float4 a0 = ((const float4*)ga)[0];
            float4 a1 = ((const float4*)ga)[1];
            bf16x8 wa;
            wa[0] = (bf16_t)a0.x; wa[1] = (bf16_t)a0.y;
            wa[2] = (bf16_t)a0.z; wa[3] = (bf16_t)a0.w;
            wa[4] = (bf16_t)a1.x; wa[5] = (bf16_t)a1.y;
            wa[6] = (bf16_t)a1.z; wa[7] = (bf16_t)a1.w;
            *(bf16x8*)&lds_a[r * 32 + c8] = wa;
            const float* gb = Pbase + (size_t)r * ND + k0 + c8;
            float4 b0 = ((const float4*)gb)[0];
            float4 b1 = ((const float4*)gb)[1];
            bf16x8 wb;
            wb[0] = (bf16_t)b0.x; wb[1] = (bf16_t)b0.y;
            wb[2] = (bf16_t)b0.z; wb[3] = (bf16_t)b0.w;
            wb[4] = (bf16_t)b1.x; wb[5] = (bf16_t)b1.y;
            wb[6] = (bf16_t)b1.z; wb[7] = (bf16_t)b1.w;
            *(bf16x8*)&lds_b[r * 32 + c8] = wb;
        }
        __syncthreads();

        // A frag: lane holds A[m=l16][k=quad*8+j]; B frag symmetric (P rows).
        bf16x8 af[4], bfr[4];
#pragma unroll
        for (int mt = 0; mt < 4; ++mt)
            af[mt] = *(const bf16x8*)&lds_a[(wm * 64 + mt * 16 + l16) * 32 + quad * 8];
#pragma unroll
        for (int nt = 0; nt < 4; ++nt)
            bfr[nt] = *(const bf16x8*)&lds_b[(wn * 64 + nt * 16 + l16) * 32 + quad * 8];
#pragma unroll
        for (int mt = 0; mt < 4; ++mt)
#pragma unroll
            for (int nt = 0; nt < 4; ++nt)
                acc[mt][nt] = __builtin_amdgcn_mfma_f32_16x16x32_bf16(
                    af[mt], bfr[nt], acc[mt][nt], 0, 0, 0);
    }

    // Epilogue. C/D layout (m89-verified): col = l16, row = quad*4 + reg.
    int row0 = tile_m * 128 + wm * 64;
    int col0 = tile_n * 128 + wn * 64;
    float ipn[4];
#pragma unroll
    for (int nt = 0; nt < 4; ++nt) ipn[nt] = inv_p[col0 + nt * 16 + l16];
    bool diag_block = (tile_m == tile_n);

    float psum[4][4];
#pragma unroll
    for (int mt = 0; mt < 4; ++mt)
#pragma unroll
        for (int r = 0; r < 4; ++r) psum[mt][r] = 0.0f;

#pragma unroll
    for (int mt = 0; mt < 4; ++mt) {
        float ia[4];
#pragma unroll
        for (int r = 0; r < 4; ++r) ia[r] = inv_a[row0 + mt * 16 + quad * 4 + r];
#pragma unroll
        for (int nt = 0; nt < 4; ++nt) {
#pragma unroll
            for (int r = 0; r < 4; ++r) {
                float sc = SCALEF * ia[r] * ipn[nt] * acc[mt][nt][r];
                // scores bounded by ~±20 -> fixed-shift exp, no max pass
                psum[mt][r] += __expf(sc - SCALEF);
                if (diag_block) {
                    int grow = row0 + mt * 16 + quad * 4 + r;
                    int gcol = col0 + nt * 16 + l16;
                    if (grow == gcol) diag[grow] = sc;
                }
            }
        }
    }

    // Reduce over the 16 lanes of each quad (the 16 columns of a tile row),
    // then one atomic per row per wave.
#pragma unroll
    for (int mt = 0; mt < 4; ++mt) {
#pragma unroll
        for (int r = 0; r < 4; ++r) {
            float v = psum[mt][r];
            v += __shfl_xor(v, 1, 64);
            v += __shfl_xor(v, 2, 64);
            v += __shfl_xor(v, 4, 64);
            v += __shfl_xor(v, 8, 64);
            if (l16 == 0) atomicAdd(&rowsum[row0 + mt * 16 + quad * 4 + r], v);
        }
    }
}

// ---------------------------------------------------------------------------
// Kernel 3: loss = mean(log(rowsum) + 20 - diag)
// ---------------------------------------------------------------------------
__global__ __launch_bounds__(256) void mnrl_finalize(const float* __restrict__ rowsum,
                                                     const float* __restrict__ diag,
                                                     float* __restrict__ out) {
    int t = threadIdx.x;
    float local = 0.0f;
    for (int i = t; i < NB; i += 256)
        local += (logf(rowsum[i]) + SCALEF) - diag[i];
#pragma unroll
    for (int off = 32; off > 0; off >>= 1) local += __shfl_down(local, off, 64);
    __shared__ float sred[4];
    if ((t & 63) == 0) sred[t >> 6] = local;
    __syncthreads();
    if (t == 0) out[0] = (sred[0] + sred[1] + sred[2] + sred[3]) / (float)NB;
}

// ---------------------------------------------------------------------------
extern "C" void kernel_launch(void* const* d_in, const int* in_sizes, int n_in,
                              void* d_out, int out_size, void* d_ws, size_t ws_size,
                              hipStream_t stream) {
    const float* A = (const float*)d_in[0];
    const float* P = (const float*)d_in[1];

    float* inv_a = (float*)d_ws;          // [4096]
    float* inv_p = inv_a + NB;            // [4096]
    float* rowsum = inv_p + NB;           // [4096]  (needs zeroing)
    float* diag = rowsum + NB;            // [4096]  (fully overwritten)

    hipMemsetAsync(rowsum, 0, NB * sizeof(float), stream);
    mnrl_norms<<<2 * NB / 1, 256, 0, stream>>>(A, P, inv_a);
    mnrl_gemm_lse<<<TILES * TILES, 256, 0, stream>>>(A, P, inv_a, inv_p, rowsum, diag);
    mnrl_finalize<<<1, 256, 0, stream>>>(rowsum, diag, (float*)d_out);
}

// Round 2
// 135.046 us; speedup vs baseline: 1.2820x; 1.2820x over previous
//
#include <hip/hip_runtime.h>
#include <math.h>

#define NB 4096
#define ND 1024
#define SCALEF 20.0f
#define TILES 32   // 4096 / 128 tiles per dimension

typedef __bf16 bf16_t;
typedef bf16_t bf16x4 __attribute__((ext_vector_type(4)));
typedef bf16_t bf16x8 __attribute__((ext_vector_type(8)));
typedef float floatx4 __attribute__((ext_vector_type(4)));

__device__ __forceinline__ void load16_to_lds(const void* g, void* l) {
    __builtin_amdgcn_global_load_lds(
        (const __attribute__((address_space(1))) void*)g,
        (__attribute__((address_space(3))) void*)l, 16, 0, 0);
}

// ---------------------------------------------------------------------------
// Kernel 1: fused L2-normalize + fp32->bf16 convert. One wave per row.
// Rows 0..4095 -> A_bf (and zero rowsum[row]); rows 4096..8191 -> P_bf.
// ---------------------------------------------------------------------------
__global__ __launch_bounds__(256) void mnrl_norm_cvt(
    const float* __restrict__ A, const float* __restrict__ P,
    bf16_t* __restrict__ Abf, bf16_t* __restrict__ Pbf,
    float* __restrict__ rowsum) {
    int row = blockIdx.x * 4 + (threadIdx.x >> 6);  // 0..8191
    int lane = threadIdx.x & 63;
    bool is_a = row < NB;
    const float* src = is_a ? (A + (size_t)row * ND)
                            : (P + (size_t)(row - NB) * ND);
    bf16_t* dst = is_a ? (Abf + (size_t)row * ND)
                       : (Pbf + (size_t)(row - NB) * ND);

    float4 v[4];
    float ss = 0.0f;
#pragma unroll
    for (int i = 0; i < 4; ++i) {
        v[i] = ((const float4*)src)[i * 64 + lane];
        ss += v[i].x * v[i].x + v[i].y * v[i].y + v[i].z * v[i].z + v[i].w * v[i].w;
    }
#pragma unroll
    for (int off = 32; off > 0; off >>= 1) ss += __shfl_xor(ss, off, 64);
    float inv = 1.0f / fmaxf(sqrtf(ss), 1e-8f);
#pragma unroll
    for (int i = 0; i < 4; ++i) {
        bf16x4 w;
        w[0] = (bf16_t)(v[i].x * inv);
        w[1] = (bf16_t)(v[i].y * inv);
        w[2] = (bf16_t)(v[i].z * inv);
        w[3] = (bf16_t)(v[i].w * inv);
        ((bf16x4*)dst)[i * 64 + lane] = w;
    }
    if (is_a && lane == 0) rowsum[row] = 0.0f;
}

// ---------------------------------------------------------------------------
// Kernel 2: 128x128-tile bf16 MFMA GEMM (pre-normalized inputs) with fused
// exp-sum (fixed shift 20) and diagonal extraction.
// BK=64, staged via global_load_lds width-16 (wave-uniform base + lane*16).
// LDS layout per row: 8 chunks of 8 bf16; chunk c stored at slot c^(row&7)
// (xor-swizzle chosen on the fetch side) -> frag ds_read_b128 spreads over
// all 8 bank groups.
// ---------------------------------------------------------------------------
__global__ __launch_bounds__(256) void mnrl_gemm_lse(
    const bf16_t* __restrict__ Abf, const bf16_t* __restrict__ Pbf,
    float* __restrict__ rowsum, float* __restrict__ diag) {
    __shared__ __align__(16) bf16_t lds_a[128 * 64];
    __shared__ __align__(16) bf16_t lds_b[128 * 64];

    // GROUP_M=8 swizzle for L2 locality
    int pid = blockIdx.x;
    const int num_in_group = 8 * TILES;
    int group_id = pid / num_in_group;
    int tile_m = group_id * 8 + (pid % 8);
    int tile_n = (pid % num_in_group) / 8;

    int t = threadIdx.x;
    int lane = t & 63;
    int wave = t >> 6;
    int wm = wave >> 1, wn = wave & 1;
    int quad = lane >> 4;
    int l16 = lane & 15;

    const bf16_t* Abase = Abf + (size_t)tile_m * 128 * ND;
    const bf16_t* Pbase = Pbf + (size_t)tile_n * 128 * ND;

    // Staging addressing (per wave-issue j): chunk16 = wave*4+j covers rows
    // chunk16*8..+8. Lane l -> row_in_chunk rl=l>>3, fetches global k-chunk
    // c=(l&7)^rl so that HW slot (l&7) holds chunk c at slot c^(row&7).
    int rl = lane >> 3;
    int cs = (lane & 7) ^ rl;          // swizzled k-chunk to fetch
    int sw16 = l16 & 7;                // read-side swizzle key

    floatx4 acc[4][4];
#pragma unroll
    for (int i = 0; i < 4; ++i)
#pragma unroll
        for (int j = 0; j < 4; ++j) acc[i][j] = (floatx4){0.f, 0.f, 0.f, 0.f};

    for (int k0 = 0; k0 < ND; k0 += 64) {
        __syncthreads();  // previous iteration's frag reads complete
#pragma unroll
        for (int j = 0; j < 4; ++j) {
            int chunk16 = wave * 4 + j;            // 0..15
            int grow = chunk16 * 8 + rl;           // 0..127
            load16_to_lds(Abase + (size_t)grow * ND + k0 + cs * 8,
                          lds_a + chunk16 * 512);
            load16_to_lds(Pbase + (size_t)grow * ND + k0 + cs * 8,
                          lds_b + chunk16 * 512);
        }
        __syncthreads();  // drains vmcnt(0): staged data visible

#pragma unroll
        for (int s = 0; s < 2; ++s) {
            bf16x8 af[4], bfr[4];
#pragma unroll
            for (int mt = 0; mt < 4; ++mt) {
                int r = wm * 64 + mt * 16 + l16;
                af[mt] = *(const bf16x8*)&lds_a[r * 64 + (((s * 4 + quad) ^ sw16) * 8)];
            }
#pragma unroll
            for (int nt = 0; nt < 4; ++nt) {
                int r = wn * 64 + nt * 16 + l16;
                bfr[nt] = *(const bf16x8*)&lds_b[r * 64 + (((s * 4 + quad) ^ sw16) * 8)];
            }
#pragma unroll
            for (int mt = 0; mt < 4; ++mt)
#pragma unroll
                for (int nt = 0; nt < 4; ++nt)
                    acc[mt][nt] = __builtin_amdgcn_mfma_f32_16x16x32_bf16(
                        af[mt], bfr[nt], acc[mt][nt], 0, 0, 0);
        }
    }

    // Epilogue. C/D layout: col = l16, row = quad*4 + reg.
    int row0 = tile_m * 128 + wm * 64;
    int col0 = tile_n * 128 + wn * 64;
    bool diag_block = (tile_m == tile_n);

    float psum[4][4];
#pragma unroll
    for (int mt = 0; mt < 4; ++mt)
#pragma unroll
        for (int r = 0; r < 4; ++r) psum[mt][r] = 0.0f;

#pragma unroll
    for (int mt = 0; mt < 4; ++mt) {
#pragma unroll
        for (int nt = 0; nt < 4; ++nt) {
#pragma unroll
            for (int r = 0; r < 4; ++r) {
                float sc = SCALEF * acc[mt][nt][r];
                psum[mt][r] += __expf(sc - SCALEF);  // scores in [-20,20]
                if (diag_block) {
                    int grow = row0 + mt * 16 + quad * 4 + r;
                    int gcol = col0 + nt * 16 + l16;
                    if (grow == gcol) diag[grow] = sc;
                }
            }
        }
    }

#pragma unroll
    for (int mt = 0; mt < 4; ++mt) {
#pragma unroll
        for (int r = 0; r < 4; ++r) {
            float v = psum[mt][r];
            v += __shfl_xor(v, 1, 64);
            v += __shfl_xor(v, 2, 64);
            v += __shfl_xor(v, 4, 64);
            v += __shfl_xor(v, 8, 64);
            if (l16 == 0) atomicAdd(&rowsum[row0 + mt * 16 + quad * 4 + r], v);
        }
    }
}

// ---------------------------------------------------------------------------
// Kernel 3: loss = mean(log(rowsum) + 20 - diag)
// ---------------------------------------------------------------------------
__global__ __launch_bounds__(256) void mnrl_finalize(const float* __restrict__ rowsum,
                                                     const float* __restrict__ diag,
                                                     float* __restrict__ out) {
    int t = threadIdx.x;
    float local = 0.0f;
    for (int i = t; i < NB; i += 256)
        local += (logf(rowsum[i]) + SCALEF) - diag[i];
#pragma unroll
    for (int off = 32; off > 0; off >>= 1) local += __shfl_down(local, off, 64);
    __shared__ float sred[4];
    if ((t & 63) == 0) sred[t >> 6] = local;
    __syncthreads();
    if (t == 0) out[0] = (sred[0] + sred[1] + sred[2] + sred[3]) / (float)NB;
}

// ---------------------------------------------------------------------------
extern "C" void kernel_launch(void* const* d_in, const int* in_sizes, int n_in,
                              void* d_out, int out_size, void* d_ws, size_t ws_size,
                              hipStream_t stream) {
    const float* A = (const float*)d_in[0];
    const float* P = (const float*)d_in[1];

    bf16_t* Abf = (bf16_t*)d_ws;                        // 8 MiB
    bf16_t* Pbf = Abf + (size_t)NB * ND;                // 8 MiB
    float* rowsum = (float*)(Pbf + (size_t)NB * ND);    // 16 KiB (zeroed in cvt)
    float* diag = rowsum + NB;                          // 16 KiB

    mnrl_norm_cvt<<<2 * NB / 4, 256, 0, stream>>>(A, P, Abf, Pbf, rowsum);
    mnrl_gemm_lse<<<TILES * TILES, 256, 0, stream>>>(Abf, Pbf, rowsum, diag);
    mnrl_finalize<<<1, 256, 0, stream>>>(rowsum, diag, (float*)d_out);
}